// Round 5
// baseline (500.296 us; speedup 1.0000x reference)
//
#include <hip/hip_runtime.h>
#include <hip/hip_bf16.h>

// Problem constants
#define B_ 4
#define S_ 2048
#define D_ 768
#define H_ 12
#define HD_ 64

typedef __attribute__((ext_vector_type(8))) short bf16x8;   // 8 bf16 in 4 VGPRs
typedef __attribute__((ext_vector_type(4))) float floatx4;  // MFMA C/D frag

// fold 1/sqrt(64) * log2(e) into Q so softmax uses raw exp2
#define QSCALE 0.18033688011112042f

__device__ __forceinline__ unsigned short f2bf(float x) {
    union { float f; unsigned int u; } v; v.f = x;
    unsigned int r = v.u + 0x7fffu + ((v.u >> 16) & 1u);  // RNE
    return (unsigned short)(r >> 16);
}

// packed 2xf32 -> 2xbf16
__device__ __forceinline__ unsigned int pk2bf(float a, float b) {
    __hip_bfloat162 h = __float22bfloat162_rn(make_float2(a, b));
    unsigned int u;
    __builtin_memcpy(&u, &h, 4);
    return u;
}

// async global->LDS, 16B per lane; lds base wave-uniform, lane i at +i*16B
__device__ __forceinline__ void gload_lds16(const void* g, void* l) {
    __builtin_amdgcn_global_load_lds(
        (const __attribute__((address_space(1))) unsigned int*)g,
        (__attribute__((address_space(3))) unsigned int*)l, 16, 0, 0);
}

// 16B of bf16 from an 8B-aligned LDS address (Ps has stride 68)
__device__ __forceinline__ bf16x8 ld_b64x2(const unsigned short* p) {
    union { bf16x8 v; unsigned long long q[2]; } u;
    u.q[0] = *(const unsigned long long*)p;
    u.q[1] = *(const unsigned long long*)(p + 4);
    return u.v;
}

// ---------------- fused prep: cast X, cast 4 weights, pack mask ----------------
// grid.x = 6144 (X) + 2304 (W: 576*4) + 6144 (mask, 8 iters each) = 14592.
__global__ void prep(const float* __restrict__ hs,
                     const float* __restrict__ w0, const float* __restrict__ w1,
                     const float* __restrict__ w2, const float* __restrict__ w3,
                     const int* __restrict__ mask,
                     unsigned short* __restrict__ Xb,
                     unsigned short* __restrict__ Wb,
                     unsigned long long* __restrict__ bits) {
    int bid = blockIdx.x;
    int t = threadIdx.x;
    if (bid < 6144) {
        int i = bid * 256 + t;
        float4 f = ((const float4*)hs)[i];
        ushort4 o;
        o.x = f2bf(f.x); o.y = f2bf(f.y); o.z = f2bf(f.z); o.w = f2bf(f.w);
        ((ushort4*)Xb)[i] = o;
    } else if (bid < 8448) {
        int q = bid - 6144;
        int wid = q / 576;
        const float* src = (wid == 0) ? w0 : (wid == 1) ? w1 : (wid == 2) ? w2 : w3;
        unsigned short* d = Wb + (size_t)wid * 589824;
        int i = (q - wid * 576) * 256 + t;
        float4 f = ((const float4*)src)[i];
        ushort4 o;
        o.x = f2bf(f.x); o.y = f2bf(f.y); o.z = f2bf(f.z); o.w = f2bf(f.w);
        ((ushort4*)d)[i] = o;
    } else {
        // mask: grid-stride, each block covers 32 contiguous wave-chunks (32 KB)
        int q = bid - 8448;                 // 0..6143
        int lane = t & 63, wv = t >> 6;
#pragma unroll
        for (int j = 0; j < 8; j++) {
            size_t gw = (size_t)q * 32 + j * 4 + wv;   // 0..196607
            size_t base = gw * 256;
            unsigned long long b0 = __ballot(mask[base + lane] != 0);
            unsigned long long b1 = __ballot(mask[base + 64 + lane] != 0);
            unsigned long long b2 = __ballot(mask[base + 128 + lane] != 0);
            unsigned long long b3 = __ballot(mask[base + 192 + lane] != 0);
            if (lane == 0) {
                bits[gw * 4 + 0] = b0; bits[gw * 4 + 1] = b1;
                bits[gw * 4 + 2] = b2; bits[gw * 4 + 3] = b3;
            }
        }
    }
}

// ---------------- QKV projection GEMM ----------------
// 128x128 tile, BK=32, double-buffered async staging (1 barrier/iter).
// R5: XCD-chunked swizzle, z-fastest decode (3 z-GEMMs sharing an X-tile
// run adjacently on one XCD; W panels stay L2-resident).
__global__ __launch_bounds__(256) void qkv_gemm(
    const unsigned short* __restrict__ Xb,
    const unsigned short* __restrict__ Wq, const unsigned short* __restrict__ Wk,
    const unsigned short* __restrict__ Wv,
    const float* __restrict__ bq, const float* __restrict__ bk,
    const float* __restrict__ bv,
    unsigned short* __restrict__ Qo, unsigned short* __restrict__ Ko,
    unsigned short* __restrict__ Vo)
{
    const int lin = blockIdx.x + 64 * (blockIdx.y + 6 * blockIdx.z); // 0..1151
    const int nn = (lin & 7) * 144 + (lin >> 3);
    const int z = nn % 3;
    const int xy = nn / 3;                 // 0..383
    const int m0 = (xy & 63) * 128;
    const int n0 = (xy >> 6) * 128;

    const unsigned short* W = (z == 0) ? Wq : (z == 1) ? Wk : Wv;
    const float* bias = (z == 0) ? bq : (z == 1) ? bk : bv;
    unsigned short* Out = (z == 0) ? Qo : (z == 1) ? Ko : Vo;
    const float scale = (z == 0) ? QSCALE : 1.0f;

    // dbuf: buf b -> As at b*8192, Bs at b*8192+4096. Epilogue reuses [0..8192).
    __shared__ alignas(16) unsigned short SMall[16384];
    unsigned short* SM = SMall;

    const int t = threadIdx.x;
    const int lane = t & 63, w = t >> 6;
    const int c = lane & 15, quad = lane >> 4;
    const int wm = (w & 1) * 64, wn = (w >> 1) * 64;

    const int srowq = lane >> 2, sc8 = (lane & 3) * 8;

    floatx4 acc[4][4];
#pragma unroll
    for (int i = 0; i < 4; i++)
#pragma unroll
        for (int j = 0; j < 4; j++) acc[i][j] = (floatx4){0.f, 0.f, 0.f, 0.f};

    // stage k-tile 0 into buf 0
#pragma unroll
    for (int i = 0; i < 2; i++) {
        int chunk = i * 4 + w;
        int row = chunk * 16 + srowq;
        gload_lds16(&Xb[(size_t)(m0 + row) * 768 + sc8], &SMall[chunk * 512]);
        gload_lds16(&W [(size_t)(n0 + row) * 768 + sc8], &SMall[4096 + chunk * 512]);
    }

    for (int it = 0; it < 24; it++) {
        const int cur = it & 1;
        __syncthreads();   // staging(it) done; buf cur^1 reads (it-1) drained
        if (it + 1 < 24) {
            int k1 = (it + 1) * 32;
#pragma unroll
            for (int i = 0; i < 2; i++) {
                int chunk = i * 4 + w;
                int row = chunk * 16 + srowq;
                gload_lds16(&Xb[(size_t)(m0 + row) * 768 + k1 + sc8],
                            &SMall[(cur ^ 1) * 8192 + chunk * 512]);
                gload_lds16(&W [(size_t)(n0 + row) * 768 + k1 + sc8],
                            &SMall[(cur ^ 1) * 8192 + 4096 + chunk * 512]);
            }
        }
        const unsigned short* As = &SMall[cur * 8192];
        const unsigned short* Bs = As + 4096;
        bf16x8 a[4], b[4];
#pragma unroll
        for (int i = 0; i < 4; i++)
            a[i] = *(const bf16x8*)&As[(wm + i * 16 + c) * 32 + quad * 8];
#pragma unroll
        for (int j = 0; j < 4; j++)
            b[j] = *(const bf16x8*)&Bs[(wn + j * 16 + c) * 32 + quad * 8];
#pragma unroll
        for (int i = 0; i < 4; i++)
#pragma unroll
            for (int j = 0; j < 4; j++)
                acc[i][j] = __builtin_amdgcn_mfma_f32_16x16x32_bf16(
                    a[i], b[j], acc[i][j], 0, 0, 0);
    }
    __syncthreads();   // all LDS reads done before epilogue reuses SMall

    const int bb = m0 >> 11, ssb = m0 & 2047;
    if (z == 2) {
        // V^T epilogue: LDS-transpose (xor-swizzled, 64n x 128m per half),
        // then coalesced 16B global stores along s.
#pragma unroll
        for (int half = 0; half < 2; half++) {
            if ((w >> 1) == half) {
#pragma unroll
                for (int j = 0; j < 4; j++) {
                    int n_l = j * 16 + c;                 // 0..63, n_l&15 == c
                    float bias_n = bias[n0 + half * 64 + n_l];
#pragma unroll
                    for (int i = 0; i < 4; i++) {
#pragma unroll
                        for (int r = 0; r < 4; r++) {
                            int m = wm + i * 16 + quad * 4 + r;
                            int ms = m ^ (c << 3);        // xor-swizzle chunks
                            SM[n_l * 128 + ms] = f2bf(acc[i][j][r] + bias_n);
                        }
                    }
                }
            }
            __syncthreads();
#pragma unroll
            for (int rb = 0; rb < 2; rb++) {
                int n_l = (t >> 3) + rb * 32;
                int ch = t & 7;
                int n_abs = n0 + half * 64 + n_l;
                int hh = n_abs >> 6, dd = n_abs & 63;
                unsigned short* dst =
                    Out + (((size_t)(bb * H_ + hh)) * 64 + dd) * S_ + ssb;
#pragma unroll
                for (int p = 0; p < 2; p++) {
                    int mc = ch + p * 8;
                    uint4 v = *(const uint4*)&SM[n_l * 128 + ((mc ^ (n_l & 15)) * 8)];
                    *(uint4*)&dst[mc * 8] = v;
                }
            }
            __syncthreads();
        }
    } else {
        // Q/K epilogue: [bh][s][d] rows contiguous in d (128B). Stage the
        // 128m x 64n half-tile ([m][8 chunks of 8], chunk ^= (m>>1)&7),
        // then 16B coalesced stores along d.
#pragma unroll
        for (int half = 0; half < 2; half++) {
            if ((w >> 1) == half) {
#pragma unroll
                for (int j = 0; j < 4; j++) {
                    float bias_n = bias[n0 + half * 64 + j * 16 + c];
#pragma unroll
                    for (int i = 0; i < 4; i++) {
#pragma unroll
                        for (int r = 0; r < 4; r++) {
                            int m = wm + i * 16 + quad * 4 + r;
                            int chunk = (j * 2 + (c >> 3)) ^ ((m >> 1) & 7);
                            SM[m * 64 + chunk * 8 + (c & 7)] =
                                f2bf((acc[i][j][r] + bias_n) * scale);
                        }
                    }
                }
            }
            __syncthreads();
            {
                int hh = (n0 >> 6) + half;
                unsigned short* dst =
                    Out + ((size_t)(bb * H_ + hh) * S_ + ssb) * 64;
#pragma unroll
                for (int i = 0; i < 4; i++) {
                    int idx = i * 256 + t;
                    int m = idx >> 3, ch = idx & 7;
                    uint4 v = *(const uint4*)&SM[m * 64 + ((ch ^ ((m >> 1) & 7)) * 8)];
                    *(uint4*)&dst[(size_t)m * 64 + ch * 8] = v;
                }
            }
            __syncthreads();
        }
    }
}

// ---------------- output projection GEMM ----------------
// 64x128 tile (768 blocks = 3/CU), BK=32, double-buffered.
// R5: XCD-chunked swizzle, m-fastest decode (Wo panel per XCD L2-resident).
__global__ __launch_bounds__(256) void out_gemm(
    const unsigned short* __restrict__ Cb, const unsigned short* __restrict__ Wo,
    const float* __restrict__ bo, float* __restrict__ out)
{
    const int lin = blockIdx.x + 128 * blockIdx.y;   // 0..767
    const int nn = (lin & 7) * 96 + (lin >> 3);
    const int m0 = (nn & 127) * 64;
    const int n0 = (nn >> 7) * 128;

    // dbuf: buf b -> As(2048) at b*6144, Bs(4096) at b*6144+2048
    __shared__ alignas(16) unsigned short SMall[12288];

    const int t = threadIdx.x;
    const int lane = t & 63, w = t >> 6;
    const int c = lane & 15, quad = lane >> 4;
    const int wm = (w & 1) * 32, wn = (w >> 1) * 64;

    const int arow = w * 16 + (lane >> 2);          // A stage row for this lane
    const int brow0 = (lane >> 2);                  // + chunk*16
    const int sc8 = (lane & 3) * 8;

    floatx4 acc[2][4];
#pragma unroll
    for (int i = 0; i < 2; i++)
#pragma unroll
        for (int j = 0; j < 4; j++) acc[i][j] = (floatx4){0.f, 0.f, 0.f, 0.f};

    // stage k-tile 0 into buf 0
    gload_lds16(&Cb[(size_t)(m0 + arow) * 768 + sc8], &SMall[w * 512]);
#pragma unroll
    for (int i = 0; i < 2; i++) {
        int chunk = i * 4 + w;
        gload_lds16(&Wo[(size_t)(n0 + chunk * 16 + brow0) * 768 + sc8],
                    &SMall[2048 + chunk * 512]);
    }

    for (int it = 0; it < 24; it++) {
        const int cur = it & 1;
        __syncthreads();
        if (it + 1 < 24) {
            int k1 = (it + 1) * 32;
            gload_lds16(&Cb[(size_t)(m0 + arow) * 768 + k1 + sc8],
                        &SMall[(cur ^ 1) * 6144 + w * 512]);
#pragma unroll
            for (int i = 0; i < 2; i++) {
                int chunk = i * 4 + w;
                gload_lds16(&Wo[(size_t)(n0 + chunk * 16 + brow0) * 768 + k1 + sc8],
                            &SMall[(cur ^ 1) * 6144 + 2048 + chunk * 512]);
            }
        }
        const unsigned short* As = &SMall[cur * 6144];
        const unsigned short* Bs = As + 2048;
        bf16x8 a[2], b[4];
#pragma unroll
        for (int i = 0; i < 2; i++)
            a[i] = *(const bf16x8*)&As[(wm + i * 16 + c) * 32 + quad * 8];
#pragma unroll
        for (int j = 0; j < 4; j++)
            b[j] = *(const bf16x8*)&Bs[(wn + j * 16 + c) * 32 + quad * 8];
#pragma unroll
        for (int i = 0; i < 2; i++)
#pragma unroll
            for (int j = 0; j < 4; j++)
                acc[i][j] = __builtin_amdgcn_mfma_f32_16x16x32_bf16(
                    a[i], b[j], acc[i][j], 0, 0, 0);
    }
    __syncthreads();

    float* SMf = (float*)SMall;    // 64m x 32n f32 = 8 KB per quarter
#pragma unroll
    for (int qtr = 0; qtr < 4; qtr++) {
        if ((w >> 1) == (qtr >> 1)) {
#pragma unroll
            for (int jj = 0; jj < 2; jj++) {
                int j = (qtr & 1) * 2 + jj;
                float bias_n = bo[n0 + wn + j * 16 + c];
                int chunk = jj * 4 + (c >> 2);
#pragma unroll
                for (int i = 0; i < 2; i++) {
#pragma unroll
                    for (int r = 0; r < 4; r++) {
                        int m = wm + i * 16 + quad * 4 + r;
                        SMf[m * 32 + ((chunk ^ (m & 7)) * 4) + (c & 3)] =
                            acc[i][j][r] + bias_n;
                    }
                }
            }
        }
        __syncthreads();
#pragma unroll
        for (int i = 0; i < 2; i++) {
            int idx = i * 256 + t;
            int m = idx >> 3, ch = idx & 7;
            float4 v = *(const float4*)&SMf[m * 32 + ((ch ^ (m & 7)) * 4)];
            *(float4*)&out[(size_t)(m0 + m) * 768 + n0 + qtr * 32 + ch * 4] = v;
        }
        __syncthreads();
    }
}

// ---------------- flash attention ----------------
// R5 = R4 (XCD swizzle, V-share, no setprio) + K-share via nt-pairs with a
// DUAL Ps buffer (per-st). Per pair: 4 K b128 reads feed BOTH q-subtiles
// (transient zz[2][2]=16 regs, same as R4's sacc[4]), exp+pack the pair's
// P-values immediately (u32 writes into Ps[w][st]). K b128 16 -> 8; total
// b128/kt/wave 24 -> 16. LDS 41472 -> 50176 (3 blocks/CU still fit; R2
// showed the R1 occupancy drop was VGPR-88-driven, not LDS-size-driven —
// so hold VGPR flat: no mask/register prefetch arrays).
__global__ __launch_bounds__(256) void attn(
    const unsigned short* __restrict__ Q, const unsigned short* __restrict__ K,
    const unsigned short* __restrict__ Vt,
    const unsigned long long* __restrict__ mbits,
    unsigned short* __restrict__ ctx)
{
    // XCD swizzle: dispatch order is x-fastest; lin % 8 = XCD.
    const int lin = blockIdx.y * 16 + blockIdx.x;      // 0..767
    const int nn = (lin & 7) * 96 + (lin >> 3);        // xcd * (768/8) + idx
    const int qt = nn & 15;                            // 0..15, 128 q-rows
    const int bh = nn >> 4;
    const int b = bh / H_, h = bh % H_;

    const unsigned short* Qp = Q + (size_t)bh * S_ * 64 + (size_t)qt * 128 * 64;
    const unsigned short* Kp = K + (size_t)bh * S_ * 64;
    const unsigned short* Vp = Vt + (size_t)bh * 64 * S_;   // [d][s]

    __shared__ alignas(16) unsigned short Ks[2][64 * 64];
    __shared__ alignas(16) unsigned short Vs[2][64 * 64];
    __shared__ alignas(16) unsigned short Ps[4][2][16 * 68];   // [wave][st]

    const int t = threadIdx.x;
    const int lane = t & 63, w = t >> 6;
    const int c = lane & 15, quad = lane >> 4;

    bf16x8 aq[2][2];
#pragma unroll
    for (int st = 0; st < 2; st++) {
        aq[st][0] = *(const bf16x8*)&Qp[(size_t)(w * 32 + st * 16 + c) * 64 + quad * 8];
        aq[st][1] = *(const bf16x8*)&Qp[(size_t)(w * 32 + st * 16 + c) * 64 + 32 + quad * 8];
    }

    const unsigned long long* mrow =
        mbits + ((size_t)h * S_ + qt * 128 + w * 32 + quad * 4) * (S_ / 64);

    floatx4 acc_o[2][4];
#pragma unroll
    for (int st = 0; st < 2; st++)
#pragma unroll
        for (int i = 0; i < 4; i++) acc_o[st][i] = (floatx4){0.f, 0.f, 0.f, 0.f};
    float lp[2][4] = {{0.f, 0.f, 0.f, 0.f}, {0.f, 0.f, 0.f, 0.f}};

    const int srow = (lane >> 3);
    const int rc0 = ((quad     ) ^ (c & 7)) * 8;
    const int rc1 = ((quad + 4) ^ (c & 7)) * 8;

#pragma unroll
    for (int i = 0; i < 2; i++) {
        int chunk = i * 4 + w;
        int row = chunk * 8 + srow;
        int col8 = (((lane & 7) ^ ((row >> 2) & 7))) * 8;
        gload_lds16(&Kp[(size_t)row * 64 + col8], &Ks[0][chunk * 512]);
        gload_lds16(&Vp[(size_t)row * S_ + col8], &Vs[0][chunk * 512]);
    }

    for (int kt = 0; kt < S_ / 64; kt++) {
        const int cur = kt & 1;
        __syncthreads();
        if (kt + 1 < S_ / 64) {
#pragma unroll
            for (int i = 0; i < 2; i++) {
                int chunk = i * 4 + w;
                int row = chunk * 8 + srow;
                int col8 = (((lane & 7) ^ ((row >> 2) & 7))) * 8;
                gload_lds16(&Kp[(size_t)((kt + 1) * 64 + row) * 64 + col8],
                            &Ks[cur ^ 1][chunk * 512]);
                gload_lds16(&Vp[(size_t)row * S_ + (kt + 1) * 64 + col8],
                            &Vs[cur ^ 1][chunk * 512]);
            }
        }

        // ---- K-shared QK^T in nt-pairs; per-pair softmax into dual Ps ----
#pragma unroll
        for (int p = 0; p < 2; p++) {
            floatx4 zz[2][2];
            zz[0][0] = (floatx4){0.f, 0.f, 0.f, 0.f};
            zz[0][1] = (floatx4){0.f, 0.f, 0.f, 0.f};
            zz[1][0] = (floatx4){0.f, 0.f, 0.f, 0.f};
            zz[1][1] = (floatx4){0.f, 0.f, 0.f, 0.f};
#pragma unroll
            for (int q2 = 0; q2 < 2; q2++) {
                int kr = 4 * c + 2 * p + q2;
                bf16x8 bk0 = *(const bf16x8*)&Ks[cur][kr * 64 + rc0];
                bf16x8 bk1 = *(const bf16x8*)&Ks[cur][kr * 64 + rc1];
                zz[0][q2] = __builtin_amdgcn_mfma_f32_16x16x32_bf16(aq[0][0], bk0, zz[0][q2], 0, 0, 0);
                zz[0][q2] = __builtin_amdgcn_mfma_f32_16x16x32_bf16(aq[0][1], bk1, zz[0][q2], 0, 0, 0);
                zz[1][q2] = __builtin_amdgcn_mfma_f32_16x16x32_bf16(aq[1][0], bk0, zz[1][q2], 0, 0, 0);
                zz[1][q2] = __builtin_amdgcn_mfma_f32_16x16x32_bf16(aq[1][1], bk1, zz[1][q2], 0, 0, 0);
            }

            asm volatile("" ::: "memory");
#pragma unroll
            for (int st = 0; st < 2; st++) {
#pragma unroll
                for (int r = 0; r < 4; r++) {
                    unsigned int n2 =
                        (unsigned int)(mrow[st * 16 * (S_ / 64) + r * (S_ / 64) + kt]
                                       >> (4 * c + 2 * p)) & 3u;
                    float p0 = (n2 & 1u) ? __builtin_amdgcn_exp2f(zz[st][0][r]) : 0.f;
                    float p1 = (n2 & 2u) ? __builtin_amdgcn_exp2f(zz[st][1][r]) : 0.f;
                    lp[st][r] += p0 + p1;
                    *(unsigned int*)&Ps[w][st][(quad * 4 + r) * 68 + 4 * c + 2 * p] =
                        pk2bf(p0, p1);
                }
            }
            asm volatile("" ::: "memory");
        }

        bf16x8 ap[2][2];
#pragma unroll
        for (int st = 0; st < 2; st++) {
            ap[st][0] = ld_b64x2(&Ps[w][st][c * 68 + quad * 8]);
            ap[st][1] = ld_b64x2(&Ps[w][st][c * 68 + 32 + quad * 8]);
        }

        // ---- shared-V PV: each bv fragment read once, feeds both st ----
#pragma unroll
        for (int nt = 0; nt < 4; nt++) {
            int vr = 4 * c + nt;                    // d = 4c+nt
            bf16x8 bv0 = *(const bf16x8*)&Vs[cur][vr * 64 + rc0];
            bf16x8 bv1 = *(const bf16x8*)&Vs[cur][vr * 64 + rc1];
#pragma unroll
            for (int st = 0; st < 2; st++) {
                acc_o[st][nt] = __builtin_amdgcn_mfma_f32_16x16x32_bf16(ap[st][0], bv0, acc_o[st][nt], 0, 0, 0);
                acc_o[st][nt] = __builtin_amdgcn_mfma_f32_16x16x32_bf16(ap[st][1], bv1, acc_o[st][nt], 0, 0, 0);
            }
        }
    }

#pragma unroll
    for (int st = 0; st < 2; st++)
#pragma unroll
        for (int r = 0; r < 4; r++) {
            float s = lp[st][r];
#pragma unroll
            for (int o = 1; o < 16; o <<= 1) s += __shfl_xor(s, o, 64);
            lp[st][r] = s;
        }

#pragma unroll
    for (int st = 0; st < 2; st++)
#pragma unroll
        for (int nt = 0; nt < 4; nt++)
#pragma unroll
            for (int r = 0; r < 4; r++) {
                int qrow = qt * 128 + w * 32 + st * 16 + quad * 4 + r;
                int dd = 4 * c + nt;
                float v = acc_o[st][nt][r] / lp[st][r];
                ctx[((size_t)b * S_ + qrow) * 768 + h * 64 + dd] = f2bf(v);
            }
}

extern "C" void kernel_launch(void* const* d_in, const int* in_sizes, int n_in,
                              void* d_out, int out_size, void* d_ws, size_t ws_size,
                              hipStream_t stream) {
    const float* hs    = (const float*)d_in[0];
    const int*   mask  = (const int*)d_in[1];
    const float* q_w   = (const float*)d_in[2];
    const float* q_b   = (const float*)d_in[3];
    const float* k_w   = (const float*)d_in[4];
    const float* k_b   = (const float*)d_in[5];
    const float* v_w   = (const float*)d_in[6];
    const float* v_b   = (const float*)d_in[7];
    const float* out_w = (const float*)d_in[8];
    const float* out_b = (const float*)d_in[9];
    float* out = (float*)d_out;

    // workspace layout (bf16 elements unless noted)
    unsigned short* Xb  = (unsigned short*)d_ws;       // 8192*768
    unsigned short* Wqb = Xb + 6291456;                // 768*768 each, x4 contiguous
    unsigned short* Wkb = Wqb + 589824;
    unsigned short* Wvb = Wkb + 589824;
    unsigned short* Wob = Wvb + 589824;
    unsigned short* Qb  = Wob + 589824;                // [B,H,S,HD]
    unsigned short* Kb  = Qb + 6291456;
    unsigned short* Vtb = Kb + 6291456;                // [B,H,HD,S] (transposed)
    unsigned short* Cb  = Vtb + 6291456;               // ctx [B,S,D]
    unsigned long long* mbits = (unsigned long long*)(Cb + 6291456); // H*S*(S/64)

    prep<<<14592, 256, 0, stream>>>(hs, q_w, k_w, v_w, out_w, mask, Xb, Wqb, mbits);
    qkv_gemm<<<dim3(64, 6, 3), 256, 0, stream>>>(Xb, Wqb, Wkb, Wvb,
                                                 q_b, k_b, v_b, Qb, Kb, Vtb);
    attn<<<dim3(16, 48), 256, 0, stream>>>(Qb, Kb, Vtb, mbits, Cb);
    out_gemm<<<dim3(128, 6), 256, 0, stream>>>(Cb, Wob, out_b, out);
}

// Round 6
// 472.483 us; speedup vs baseline: 1.0589x; 1.0589x over previous
//
#include <hip/hip_runtime.h>
#include <hip/hip_bf16.h>

// Problem constants
#define B_ 4
#define S_ 2048
#define D_ 768
#define H_ 12
#define HD_ 64

typedef __attribute__((ext_vector_type(8))) short bf16x8;   // 8 bf16 in 4 VGPRs
typedef __attribute__((ext_vector_type(4))) float floatx4;  // MFMA C/D frag

// fold 1/sqrt(64) * log2(e) into Q so softmax uses raw exp2
#define QSCALE 0.18033688011112042f

__device__ __forceinline__ unsigned short f2bf(float x) {
    union { float f; unsigned int u; } v; v.f = x;
    unsigned int r = v.u + 0x7fffu + ((v.u >> 16) & 1u);  // RNE
    return (unsigned short)(r >> 16);
}

// packed 2xf32 -> 2xbf16
__device__ __forceinline__ unsigned int pk2bf(float a, float b) {
    __hip_bfloat162 h = __float22bfloat162_rn(make_float2(a, b));
    unsigned int u;
    __builtin_memcpy(&u, &h, 4);
    return u;
}

// async global->LDS, 16B per lane; lds base wave-uniform, lane i at +i*16B
__device__ __forceinline__ void gload_lds16(const void* g, void* l) {
    __builtin_amdgcn_global_load_lds(
        (const __attribute__((address_space(1))) unsigned int*)g,
        (__attribute__((address_space(3))) unsigned int*)l, 16, 0, 0);
}

// 16B of bf16 from an 8B-aligned LDS address (Ps has stride 68)
__device__ __forceinline__ bf16x8 ld_b64x2(const unsigned short* p) {
    union { bf16x8 v; unsigned long long q[2]; } u;
    u.q[0] = *(const unsigned long long*)p;
    u.q[1] = *(const unsigned long long*)(p + 4);
    return u.v;
}

// ---------------- fused prep: cast X, cast 4 weights, pack mask ----------------
// grid.x = 6144 (X) + 2304 (W: 576*4) + 49152 (mask) = 57600, block 256.
__global__ void prep(const float* __restrict__ hs,
                     const float* __restrict__ w0, const float* __restrict__ w1,
                     const float* __restrict__ w2, const float* __restrict__ w3,
                     const int* __restrict__ mask,
                     unsigned short* __restrict__ Xb,
                     unsigned short* __restrict__ Wb,
                     unsigned long long* __restrict__ bits) {
    int bid = blockIdx.x;
    int t = threadIdx.x;
    if (bid < 6144) {
        int i = bid * 256 + t;
        float4 f = ((const float4*)hs)[i];
        ushort4 o;
        o.x = f2bf(f.x); o.y = f2bf(f.y); o.z = f2bf(f.z); o.w = f2bf(f.w);
        ((ushort4*)Xb)[i] = o;
    } else if (bid < 8448) {
        int q = bid - 6144;
        int wid = q / 576;
        const float* src = (wid == 0) ? w0 : (wid == 1) ? w1 : (wid == 2) ? w2 : w3;
        unsigned short* d = Wb + (size_t)wid * 589824;
        int i = (q - wid * 576) * 256 + t;
        float4 f = ((const float4*)src)[i];
        ushort4 o;
        o.x = f2bf(f.x); o.y = f2bf(f.y); o.z = f2bf(f.z); o.w = f2bf(f.w);
        ((ushort4*)d)[i] = o;
    } else {
        size_t gw = ((size_t)(bid - 8448) * 256 + t) >> 6;   // wave id
        int lane = t & 63;
        size_t base = gw * 256;
        unsigned long long b0 = __ballot(mask[base + lane] != 0);
        unsigned long long b1 = __ballot(mask[base + 64 + lane] != 0);
        unsigned long long b2 = __ballot(mask[base + 128 + lane] != 0);
        unsigned long long b3 = __ballot(mask[base + 192 + lane] != 0);
        if (lane == 0) {
            bits[gw * 4 + 0] = b0; bits[gw * 4 + 1] = b1;
            bits[gw * 4 + 2] = b2; bits[gw * 4 + 3] = b3;
        }
    }
}

// ---------------- QKV projection GEMM ----------------
// 128x128 tile, BK=32, DOUBLE-BUFFERED async staging (1 barrier/iter).
// Q pre-scaled by QSCALE. Q/K -> [B,H,S,HD] coalesced via LDS transpose;
// V -> [B,H,HD,S] coalesced via LDS transpose. (R4 version, no swizzle.)
__global__ __launch_bounds__(256) void qkv_gemm(
    const unsigned short* __restrict__ Xb,
    const unsigned short* __restrict__ Wq, const unsigned short* __restrict__ Wk,
    const unsigned short* __restrict__ Wv,
    const float* __restrict__ bq, const float* __restrict__ bk,
    const float* __restrict__ bv,
    unsigned short* __restrict__ Qo, unsigned short* __restrict__ Ko,
    unsigned short* __restrict__ Vo)
{
    const int z = blockIdx.z;
    const unsigned short* W = (z == 0) ? Wq : (z == 1) ? Wk : Wv;
    const float* bias = (z == 0) ? bq : (z == 1) ? bk : bv;
    unsigned short* Out = (z == 0) ? Qo : (z == 1) ? Ko : Vo;
    const float scale = (z == 0) ? QSCALE : 1.0f;

    const int m0 = blockIdx.x * 128;
    const int n0 = blockIdx.y * 128;

    // dbuf: buf b -> As at b*8192, Bs at b*8192+4096. Epilogue reuses [0..8192).
    __shared__ alignas(16) unsigned short SMall[16384];
    unsigned short* SM = SMall;

    const int t = threadIdx.x;
    const int lane = t & 63, w = t >> 6;
    const int c = lane & 15, quad = lane >> 4;
    const int wm = (w & 1) * 64, wn = (w >> 1) * 64;

    const int srowq = lane >> 2, sc8 = (lane & 3) * 8;

    floatx4 acc[4][4];
#pragma unroll
    for (int i = 0; i < 4; i++)
#pragma unroll
        for (int j = 0; j < 4; j++) acc[i][j] = (floatx4){0.f, 0.f, 0.f, 0.f};

    // stage k-tile 0 into buf 0
#pragma unroll
    for (int i = 0; i < 2; i++) {
        int chunk = i * 4 + w;
        int row = chunk * 16 + srowq;
        gload_lds16(&Xb[(size_t)(m0 + row) * 768 + sc8], &SMall[chunk * 512]);
        gload_lds16(&W [(size_t)(n0 + row) * 768 + sc8], &SMall[4096 + chunk * 512]);
    }

    for (int it = 0; it < 24; it++) {
        const int cur = it & 1;
        __syncthreads();   // staging(it) done; buf cur^1 reads (it-1) drained
        if (it + 1 < 24) {
            int k1 = (it + 1) * 32;
#pragma unroll
            for (int i = 0; i < 2; i++) {
                int chunk = i * 4 + w;
                int row = chunk * 16 + srowq;
                gload_lds16(&Xb[(size_t)(m0 + row) * 768 + k1 + sc8],
                            &SMall[(cur ^ 1) * 8192 + chunk * 512]);
                gload_lds16(&W [(size_t)(n0 + row) * 768 + k1 + sc8],
                            &SMall[(cur ^ 1) * 8192 + 4096 + chunk * 512]);
            }
        }
        const unsigned short* As = &SMall[cur * 8192];
        const unsigned short* Bs = As + 4096;
        bf16x8 a[4], b[4];
#pragma unroll
        for (int i = 0; i < 4; i++)
            a[i] = *(const bf16x8*)&As[(wm + i * 16 + c) * 32 + quad * 8];
#pragma unroll
        for (int j = 0; j < 4; j++)
            b[j] = *(const bf16x8*)&Bs[(wn + j * 16 + c) * 32 + quad * 8];
#pragma unroll
        for (int i = 0; i < 4; i++)
#pragma unroll
            for (int j = 0; j < 4; j++)
                acc[i][j] = __builtin_amdgcn_mfma_f32_16x16x32_bf16(
                    a[i], b[j], acc[i][j], 0, 0, 0);
    }
    __syncthreads();   // all LDS reads done before epilogue reuses SMall

    const int bb = m0 >> 11, ssb = m0 & 2047;
    if (z == 2) {
        // V^T epilogue: LDS-transpose (xor-swizzled, 64n x 128m per half),
        // then coalesced 16B global stores along s.
#pragma unroll
        for (int half = 0; half < 2; half++) {
            if ((w >> 1) == half) {
#pragma unroll
                for (int j = 0; j < 4; j++) {
                    int n_l = j * 16 + c;                 // 0..63, n_l&15 == c
                    float bias_n = bias[n0 + half * 64 + n_l];
#pragma unroll
                    for (int i = 0; i < 4; i++) {
#pragma unroll
                        for (int r = 0; r < 4; r++) {
                            int m = wm + i * 16 + quad * 4 + r;
                            int ms = m ^ (c << 3);        // xor-swizzle chunks
                            SM[n_l * 128 + ms] = f2bf(acc[i][j][r] + bias_n);
                        }
                    }
                }
            }
            __syncthreads();
#pragma unroll
            for (int rb = 0; rb < 2; rb++) {
                int n_l = (t >> 3) + rb * 32;
                int ch = t & 7;
                int n_abs = n0 + half * 64 + n_l;
                int hh = n_abs >> 6, dd = n_abs & 63;
                unsigned short* dst =
                    Out + (((size_t)(bb * H_ + hh)) * 64 + dd) * S_ + ssb;
#pragma unroll
                for (int p = 0; p < 2; p++) {
                    int mc = ch + p * 8;
                    uint4 v = *(const uint4*)&SM[n_l * 128 + ((mc ^ (n_l & 15)) * 8)];
                    *(uint4*)&dst[mc * 8] = v;
                }
            }
            __syncthreads();
        }
    } else {
        // Q/K epilogue: [bh][s][d] rows contiguous in d (128B). Stage the
        // 128m x 64n half-tile ([m][8 chunks of 8], chunk ^= (m>>1)&7),
        // then 16B coalesced stores along d.
#pragma unroll
        for (int half = 0; half < 2; half++) {
            if ((w >> 1) == half) {
#pragma unroll
                for (int j = 0; j < 4; j++) {
                    float bias_n = bias[n0 + half * 64 + j * 16 + c];
#pragma unroll
                    for (int i = 0; i < 4; i++) {
#pragma unroll
                        for (int r = 0; r < 4; r++) {
                            int m = wm + i * 16 + quad * 4 + r;
                            int chunk = (j * 2 + (c >> 3)) ^ ((m >> 1) & 7);
                            SM[m * 64 + chunk * 8 + (c & 7)] =
                                f2bf((acc[i][j][r] + bias_n) * scale);
                        }
                    }
                }
            }
            __syncthreads();
            {
                int hh = (n0 >> 6) + half;
                unsigned short* dst =
                    Out + ((size_t)(bb * H_ + hh) * S_ + ssb) * 64;
#pragma unroll
                for (int i = 0; i < 4; i++) {
                    int idx = i * 256 + t;
                    int m = idx >> 3, ch = idx & 7;
                    uint4 v = *(const uint4*)&SM[m * 64 + ((ch ^ ((m >> 1) & 7)) * 8)];
                    *(uint4*)&dst[(size_t)m * 64 + ch * 8] = v;
                }
            }
            __syncthreads();
        }
    }
}

// ---------------- output projection GEMM ----------------
// 64x128 tile (grid 128x6 = 768 blocks = 3/CU), BK=32, double-buffered.
// Coalesced f32 epilogue via LDS transpose. (R4 version, no swizzle.)
__global__ __launch_bounds__(256) void out_gemm(
    const unsigned short* __restrict__ Cb, const unsigned short* __restrict__ Wo,
    const float* __restrict__ bo, float* __restrict__ out)
{
    const int m0 = blockIdx.x * 64;
    const int n0 = blockIdx.y * 128;

    // dbuf: buf b -> As(2048) at b*6144, Bs(4096) at b*6144+2048
    __shared__ alignas(16) unsigned short SMall[12288];

    const int t = threadIdx.x;
    const int lane = t & 63, w = t >> 6;
    const int c = lane & 15, quad = lane >> 4;
    const int wm = (w & 1) * 32, wn = (w >> 1) * 64;

    const int arow = w * 16 + (lane >> 2);          // A stage row for this lane
    const int brow0 = (lane >> 2);                  // + chunk*16
    const int sc8 = (lane & 3) * 8;

    floatx4 acc[2][4];
#pragma unroll
    for (int i = 0; i < 2; i++)
#pragma unroll
        for (int j = 0; j < 4; j++) acc[i][j] = (floatx4){0.f, 0.f, 0.f, 0.f};

    // stage k-tile 0 into buf 0
    gload_lds16(&Cb[(size_t)(m0 + arow) * 768 + sc8], &SMall[w * 512]);
#pragma unroll
    for (int i = 0; i < 2; i++) {
        int chunk = i * 4 + w;
        gload_lds16(&Wo[(size_t)(n0 + chunk * 16 + brow0) * 768 + sc8],
                    &SMall[2048 + chunk * 512]);
    }

    for (int it = 0; it < 24; it++) {
        const int cur = it & 1;
        __syncthreads();
        if (it + 1 < 24) {
            int k1 = (it + 1) * 32;
            gload_lds16(&Cb[(size_t)(m0 + arow) * 768 + k1 + sc8],
                        &SMall[(cur ^ 1) * 6144 + w * 512]);
#pragma unroll
            for (int i = 0; i < 2; i++) {
                int chunk = i * 4 + w;
                gload_lds16(&Wo[(size_t)(n0 + chunk * 16 + brow0) * 768 + k1 + sc8],
                            &SMall[(cur ^ 1) * 6144 + 2048 + chunk * 512]);
            }
        }
        const unsigned short* As = &SMall[cur * 6144];
        const unsigned short* Bs = As + 2048;
        bf16x8 a[2], b[4];
#pragma unroll
        for (int i = 0; i < 2; i++)
            a[i] = *(const bf16x8*)&As[(wm + i * 16 + c) * 32 + quad * 8];
#pragma unroll
        for (int j = 0; j < 4; j++)
            b[j] = *(const bf16x8*)&Bs[(wn + j * 16 + c) * 32 + quad * 8];
#pragma unroll
        for (int i = 0; i < 2; i++)
#pragma unroll
            for (int j = 0; j < 4; j++)
                acc[i][j] = __builtin_amdgcn_mfma_f32_16x16x32_bf16(
                    a[i], b[j], acc[i][j], 0, 0, 0);
    }
    __syncthreads();

    float* SMf = (float*)SMall;    // 64m x 32n f32 = 8 KB per quarter
#pragma unroll
    for (int qtr = 0; qtr < 4; qtr++) {
        if ((w >> 1) == (qtr >> 1)) {
#pragma unroll
            for (int jj = 0; jj < 2; jj++) {
                int j = (qtr & 1) * 2 + jj;
                float bias_n = bo[n0 + wn + j * 16 + c];
                int chunk = jj * 4 + (c >> 2);
#pragma unroll
                for (int i = 0; i < 2; i++) {
#pragma unroll
                    for (int r = 0; r < 4; r++) {
                        int m = wm + i * 16 + quad * 4 + r;
                        SMf[m * 32 + ((chunk ^ (m & 7)) * 4) + (c & 3)] =
                            acc[i][j][r] + bias_n;
                    }
                }
            }
        }
        __syncthreads();
#pragma unroll
        for (int i = 0; i < 2; i++) {
            int idx = i * 256 + t;
            int m = idx >> 3, ch = idx & 7;
            float4 v = *(const float4*)&SMf[m * 32 + ((ch ^ (m & 7)) * 4)];
            *(float4*)&out[(size_t)(m0 + m) * 768 + n0 + qtr * 32 + ch * 4] = v;
        }
        __syncthreads();
    }
}

// ---------------- flash attention ----------------
// R6 = R5 structure (XCD swizzle, V-share, K-share nt-pairs, dual Ps,
// no setprio) + FIX of R5's regression: the asm "memory" clobbers forced
// mrow to be re-loaded from global 16x per kt inside the softmax critical
// path (each ~200-300cy L2). Now the 8 mask words are loaded ONCE per kt
// into registers at the TOP of the iteration, BEFORE the staging gloads
// (vmcnt is FIFO oldest-first, so waiting on them in softmax does not
// drain staging), and they fly during the QK MFMA cluster. Register
// values are immune to the clobbers. VGPR ~+16 transient (<128 cliff).
__global__ __launch_bounds__(256) void attn(
    const unsigned short* __restrict__ Q, const unsigned short* __restrict__ K,
    const unsigned short* __restrict__ Vt,
    const unsigned long long* __restrict__ mbits,
    unsigned short* __restrict__ ctx)
{
    // XCD swizzle: dispatch order is x-fastest; lin % 8 = XCD.
    const int lin = blockIdx.y * 16 + blockIdx.x;      // 0..767
    const int nn = (lin & 7) * 96 + (lin >> 3);        // xcd * (768/8) + idx
    const int qt = nn & 15;                            // 0..15, 128 q-rows
    const int bh = nn >> 4;
    const int b = bh / H_, h = bh % H_;

    const unsigned short* Qp = Q + (size_t)bh * S_ * 64 + (size_t)qt * 128 * 64;
    const unsigned short* Kp = K + (size_t)bh * S_ * 64;
    const unsigned short* Vp = Vt + (size_t)bh * 64 * S_;   // [d][s]

    __shared__ alignas(16) unsigned short Ks[2][64 * 64];
    __shared__ alignas(16) unsigned short Vs[2][64 * 64];
    __shared__ alignas(16) unsigned short Ps[4][2][16 * 68];   // [wave][st]

    const int t = threadIdx.x;
    const int lane = t & 63, w = t >> 6;
    const int c = lane & 15, quad = lane >> 4;

    bf16x8 aq[2][2];
#pragma unroll
    for (int st = 0; st < 2; st++) {
        aq[st][0] = *(const bf16x8*)&Qp[(size_t)(w * 32 + st * 16 + c) * 64 + quad * 8];
        aq[st][1] = *(const bf16x8*)&Qp[(size_t)(w * 32 + st * 16 + c) * 64 + 32 + quad * 8];
    }

    const unsigned long long* mrow =
        mbits + ((size_t)h * S_ + qt * 128 + w * 32 + quad * 4) * (S_ / 64);

    floatx4 acc_o[2][4];
#pragma unroll
    for (int st = 0; st < 2; st++)
#pragma unroll
        for (int i = 0; i < 4; i++) acc_o[st][i] = (floatx4){0.f, 0.f, 0.f, 0.f};
    float lp[2][4] = {{0.f, 0.f, 0.f, 0.f}, {0.f, 0.f, 0.f, 0.f}};

    const int srow = (lane >> 3);
    const int rc0 = ((quad     ) ^ (c & 7)) * 8;
    const int rc1 = ((quad + 4) ^ (c & 7)) * 8;

#pragma unroll
    for (int i = 0; i < 2; i++) {
        int chunk = i * 4 + w;
        int row = chunk * 8 + srow;
        int col8 = (((lane & 7) ^ ((row >> 2) & 7))) * 8;
        gload_lds16(&Kp[(size_t)row * 64 + col8], &Ks[0][chunk * 512]);
        gload_lds16(&Vp[(size_t)row * S_ + col8], &Vs[0][chunk * 512]);
    }

    for (int kt = 0; kt < S_ / 64; kt++) {
        const int cur = kt & 1;
        __syncthreads();

        // mask words for THIS kt -> registers, issued BEFORE staging so
        // the softmax wait (FIFO oldest-first) doesn't drain staging.
        unsigned long long mk[2][4];
#pragma unroll
        for (int st = 0; st < 2; st++)
#pragma unroll
            for (int r = 0; r < 4; r++)
                mk[st][r] = mrow[st * 512 + r * 32 + kt];

        if (kt + 1 < S_ / 64) {
#pragma unroll
            for (int i = 0; i < 2; i++) {
                int chunk = i * 4 + w;
                int row = chunk * 8 + srow;
                int col8 = (((lane & 7) ^ ((row >> 2) & 7))) * 8;
                gload_lds16(&Kp[(size_t)((kt + 1) * 64 + row) * 64 + col8],
                            &Ks[cur ^ 1][chunk * 512]);
                gload_lds16(&Vp[(size_t)row * S_ + (kt + 1) * 64 + col8],
                            &Vs[cur ^ 1][chunk * 512]);
            }
        }

        // ---- K-shared QK^T in nt-pairs; per-pair softmax into dual Ps ----
#pragma unroll
        for (int p = 0; p < 2; p++) {
            floatx4 zz[2][2];
            zz[0][0] = (floatx4){0.f, 0.f, 0.f, 0.f};
            zz[0][1] = (floatx4){0.f, 0.f, 0.f, 0.f};
            zz[1][0] = (floatx4){0.f, 0.f, 0.f, 0.f};
            zz[1][1] = (floatx4){0.f, 0.f, 0.f, 0.f};
#pragma unroll
            for (int q2 = 0; q2 < 2; q2++) {
                int kr = 4 * c + 2 * p + q2;
                bf16x8 bk0 = *(const bf16x8*)&Ks[cur][kr * 64 + rc0];
                bf16x8 bk1 = *(const bf16x8*)&Ks[cur][kr * 64 + rc1];
                zz[0][q2] = __builtin_amdgcn_mfma_f32_16x16x32_bf16(aq[0][0], bk0, zz[0][q2], 0, 0, 0);
                zz[0][q2] = __builtin_amdgcn_mfma_f32_16x16x32_bf16(aq[0][1], bk1, zz[0][q2], 0, 0, 0);
                zz[1][q2] = __builtin_amdgcn_mfma_f32_16x16x32_bf16(aq[1][0], bk0, zz[1][q2], 0, 0, 0);
                zz[1][q2] = __builtin_amdgcn_mfma_f32_16x16x32_bf16(aq[1][1], bk1, zz[1][q2], 0, 0, 0);
            }

            asm volatile("" ::: "memory");
#pragma unroll
            for (int st = 0; st < 2; st++) {
#pragma unroll
                for (int r = 0; r < 4; r++) {
                    unsigned int n2 =
                        (unsigned int)(mk[st][r] >> (4 * c + 2 * p)) & 3u;
                    float p0 = (n2 & 1u) ? __builtin_amdgcn_exp2f(zz[st][0][r]) : 0.f;
                    float p1 = (n2 & 2u) ? __builtin_amdgcn_exp2f(zz[st][1][r]) : 0.f;
                    lp[st][r] += p0 + p1;
                    *(unsigned int*)&Ps[w][st][(quad * 4 + r) * 68 + 4 * c + 2 * p] =
                        pk2bf(p0, p1);
                }
            }
            asm volatile("" ::: "memory");
        }

        bf16x8 ap[2][2];
#pragma unroll
        for (int st = 0; st < 2; st++) {
            ap[st][0] = ld_b64x2(&Ps[w][st][c * 68 + quad * 8]);
            ap[st][1] = ld_b64x2(&Ps[w][st][c * 68 + 32 + quad * 8]);
        }

        // ---- shared-V PV: each bv fragment read once, feeds both st ----
#pragma unroll
        for (int nt = 0; nt < 4; nt++) {
            int vr = 4 * c + nt;                    // d = 4c+nt
            bf16x8 bv0 = *(const bf16x8*)&Vs[cur][vr * 64 + rc0];
            bf16x8 bv1 = *(const bf16x8*)&Vs[cur][vr * 64 + rc1];
#pragma unroll
            for (int st = 0; st < 2; st++) {
                acc_o[st][nt] = __builtin_amdgcn_mfma_f32_16x16x32_bf16(ap[st][0], bv0, acc_o[st][nt], 0, 0, 0);
                acc_o[st][nt] = __builtin_amdgcn_mfma_f32_16x16x32_bf16(ap[st][1], bv1, acc_o[st][nt], 0, 0, 0);
            }
        }
    }

#pragma unroll
    for (int st = 0; st < 2; st++)
#pragma unroll
        for (int r = 0; r < 4; r++) {
            float s = lp[st][r];
#pragma unroll
            for (int o = 1; o < 16; o <<= 1) s += __shfl_xor(s, o, 64);
            lp[st][r] = s;
        }

#pragma unroll
    for (int st = 0; st < 2; st++)
#pragma unroll
        for (int nt = 0; nt < 4; nt++)
#pragma unroll
            for (int r = 0; r < 4; r++) {
                int qrow = qt * 128 + w * 32 + st * 16 + quad * 4 + r;
                int dd = 4 * c + nt;
                float v = acc_o[st][nt][r] / lp[st][r];
                ctx[((size_t)b * S_ + qrow) * 768 + h * 64 + dd] = f2bf(v);
            }
}

extern "C" void kernel_launch(void* const* d_in, const int* in_sizes, int n_in,
                              void* d_out, int out_size, void* d_ws, size_t ws_size,
                              hipStream_t stream) {
    const float* hs    = (const float*)d_in[0];
    const int*   mask  = (const int*)d_in[1];
    const float* q_w   = (const float*)d_in[2];
    const float* q_b   = (const float*)d_in[3];
    const float* k_w   = (const float*)d_in[4];
    const float* k_b   = (const float*)d_in[5];
    const float* v_w   = (const float*)d_in[6];
    const float* v_b   = (const float*)d_in[7];
    const float* out_w = (const float*)d_in[8];
    const float* out_b = (const float*)d_in[9];
    float* out = (float*)d_out;

    // workspace layout (bf16 elements unless noted)
    unsigned short* Xb  = (unsigned short*)d_ws;       // 8192*768
    unsigned short* Wqb = Xb + 6291456;                // 768*768 each, x4 contiguous
    unsigned short* Wkb = Wqb + 589824;
    unsigned short* Wvb = Wkb + 589824;
    unsigned short* Wob = Wvb + 589824;
    unsigned short* Qb  = Wob + 589824;                // [B,H,S,HD]
    unsigned short* Kb  = Qb + 6291456;
    unsigned short* Vtb = Kb + 6291456;                // [B,H,HD,S] (transposed)
    unsigned short* Cb  = Vtb + 6291456;               // ctx [B,S,D]
    unsigned long long* mbits = (unsigned long long*)(Cb + 6291456); // H*S*(S/64)

    prep<<<57600, 256, 0, stream>>>(hs, q_w, k_w, v_w, out_w, mask, Xb, Wqb, mbits);
    qkv_gemm<<<dim3(64, 6, 3), 256, 0, stream>>>(Xb, Wqb, Wkb, Wvb,
                                                 q_b, k_b, v_b, Qb, Kb, Vtb);
    attn<<<dim3(16, 48), 256, 0, stream>>>(Qb, Kb, Vtb, mbits, Cb);
    out_gemm<<<dim3(128, 6), 256, 0, stream>>>(Cb, Wob, out_b, out);
}

// Round 7
// 468.854 us; speedup vs baseline: 1.0671x; 1.0077x over previous
//
#include <hip/hip_runtime.h>
#include <hip/hip_bf16.h>

// Problem constants
#define B_ 4
#define S_ 2048
#define D_ 768
#define H_ 12
#define HD_ 64

typedef __attribute__((ext_vector_type(8))) short bf16x8;   // 8 bf16 in 4 VGPRs
typedef __attribute__((ext_vector_type(4))) float floatx4;  // MFMA C/D frag

// fold 1/sqrt(64) * log2(e) into Q so softmax uses raw exp2
#define QSCALE 0.18033688011112042f

__device__ __forceinline__ unsigned short f2bf(float x) {
    union { float f; unsigned int u; } v; v.f = x;
    unsigned int r = v.u + 0x7fffu + ((v.u >> 16) & 1u);  // RNE
    return (unsigned short)(r >> 16);
}

// packed 2xf32 -> 2xbf16
__device__ __forceinline__ unsigned int pk2bf(float a, float b) {
    __hip_bfloat162 h = __float22bfloat162_rn(make_float2(a, b));
    unsigned int u;
    __builtin_memcpy(&u, &h, 4);
    return u;
}

// async global->LDS, 16B per lane; lds base wave-uniform, lane i at +i*16B
__device__ __forceinline__ void gload_lds16(const void* g, void* l) {
    __builtin_amdgcn_global_load_lds(
        (const __attribute__((address_space(1))) unsigned int*)g,
        (__attribute__((address_space(3))) unsigned int*)l, 16, 0, 0);
}

// ---------------- fused prep: cast X, cast 4 weights, pack mask ----------------
// grid.x = 6144 (X) + 2304 (W: 576*4) + 49152 (mask) = 57600, block 256.
__global__ void prep(const float* __restrict__ hs,
                     const float* __restrict__ w0, const float* __restrict__ w1,
                     const float* __restrict__ w2, const float* __restrict__ w3,
                     const int* __restrict__ mask,
                     unsigned short* __restrict__ Xb,
                     unsigned short* __restrict__ Wb,
                     unsigned long long* __restrict__ bits) {
    int bid = blockIdx.x;
    int t = threadIdx.x;
    if (bid < 6144) {
        int i = bid * 256 + t;
        float4 f = ((const float4*)hs)[i];
        ushort4 o;
        o.x = f2bf(f.x); o.y = f2bf(f.y); o.z = f2bf(f.z); o.w = f2bf(f.w);
        ((ushort4*)Xb)[i] = o;
    } else if (bid < 8448) {
        int q = bid - 6144;
        int wid = q / 576;
        const float* src = (wid == 0) ? w0 : (wid == 1) ? w1 : (wid == 2) ? w2 : w3;
        unsigned short* d = Wb + (size_t)wid * 589824;
        int i = (q - wid * 576) * 256 + t;
        float4 f = ((const float4*)src)[i];
        ushort4 o;
        o.x = f2bf(f.x); o.y = f2bf(f.y); o.z = f2bf(f.z); o.w = f2bf(f.w);
        ((ushort4*)d)[i] = o;
    } else {
        size_t gw = ((size_t)(bid - 8448) * 256 + t) >> 6;   // wave id
        int lane = t & 63;
        size_t base = gw * 256;
        unsigned long long b0 = __ballot(mask[base + lane] != 0);
        unsigned long long b1 = __ballot(mask[base + 64 + lane] != 0);
        unsigned long long b2 = __ballot(mask[base + 128 + lane] != 0);
        unsigned long long b3 = __ballot(mask[base + 192 + lane] != 0);
        if (lane == 0) {
            bits[gw * 4 + 0] = b0; bits[gw * 4 + 1] = b1;
            bits[gw * 4 + 2] = b2; bits[gw * 4 + 3] = b3;
        }
    }
}

// ---------------- QKV projection GEMM ----------------
// 128x128 tile, BK=32, DOUBLE-BUFFERED async staging (1 barrier/iter).
// Q pre-scaled by QSCALE. Q/K -> [B,H,S,HD] coalesced via LDS transpose;
// V -> [B,H,HD,S] coalesced via LDS transpose.
__global__ __launch_bounds__(256) void qkv_gemm(
    const unsigned short* __restrict__ Xb,
    const unsigned short* __restrict__ Wq, const unsigned short* __restrict__ Wk,
    const unsigned short* __restrict__ Wv,
    const float* __restrict__ bq, const float* __restrict__ bk,
    const float* __restrict__ bv,
    unsigned short* __restrict__ Qo, unsigned short* __restrict__ Ko,
    unsigned short* __restrict__ Vo)
{
    const int z = blockIdx.z;
    const unsigned short* W = (z == 0) ? Wq : (z == 1) ? Wk : Wv;
    const float* bias = (z == 0) ? bq : (z == 1) ? bk : bv;
    unsigned short* Out = (z == 0) ? Qo : (z == 1) ? Ko : Vo;
    const float scale = (z == 0) ? QSCALE : 1.0f;

    const int m0 = blockIdx.x * 128;
    const int n0 = blockIdx.y * 128;

    // dbuf: buf b -> As at b*8192, Bs at b*8192+4096. Epilogue reuses [0..8192).
    __shared__ alignas(16) unsigned short SMall[16384];
    unsigned short* SM = SMall;

    const int t = threadIdx.x;
    const int lane = t & 63, w = t >> 6;
    const int c = lane & 15, quad = lane >> 4;
    const int wm = (w & 1) * 64, wn = (w >> 1) * 64;

    const int srowq = lane >> 2, sc8 = (lane & 3) * 8;

    floatx4 acc[4][4];
#pragma unroll
    for (int i = 0; i < 4; i++)
#pragma unroll
        for (int j = 0; j < 4; j++) acc[i][j] = (floatx4){0.f, 0.f, 0.f, 0.f};

    // stage k-tile 0 into buf 0
#pragma unroll
    for (int i = 0; i < 2; i++) {
        int chunk = i * 4 + w;
        int row = chunk * 16 + srowq;
        gload_lds16(&Xb[(size_t)(m0 + row) * 768 + sc8], &SMall[chunk * 512]);
        gload_lds16(&W [(size_t)(n0 + row) * 768 + sc8], &SMall[4096 + chunk * 512]);
    }

    for (int it = 0; it < 24; it++) {
        const int cur = it & 1;
        __syncthreads();   // staging(it) done; buf cur^1 reads (it-1) drained
        if (it + 1 < 24) {
            int k1 = (it + 1) * 32;
#pragma unroll
            for (int i = 0; i < 2; i++) {
                int chunk = i * 4 + w;
                int row = chunk * 16 + srowq;
                gload_lds16(&Xb[(size_t)(m0 + row) * 768 + k1 + sc8],
                            &SMall[(cur ^ 1) * 8192 + chunk * 512]);
                gload_lds16(&W [(size_t)(n0 + row) * 768 + k1 + sc8],
                            &SMall[(cur ^ 1) * 8192 + 4096 + chunk * 512]);
            }
        }
        const unsigned short* As = &SMall[cur * 8192];
        const unsigned short* Bs = As + 4096;
        bf16x8 a[4], b[4];
#pragma unroll
        for (int i = 0; i < 4; i++)
            a[i] = *(const bf16x8*)&As[(wm + i * 16 + c) * 32 + quad * 8];
#pragma unroll
        for (int j = 0; j < 4; j++)
            b[j] = *(const bf16x8*)&Bs[(wn + j * 16 + c) * 32 + quad * 8];
#pragma unroll
        for (int i = 0; i < 4; i++)
#pragma unroll
            for (int j = 0; j < 4; j++)
                acc[i][j] = __builtin_amdgcn_mfma_f32_16x16x32_bf16(
                    a[i], b[j], acc[i][j], 0, 0, 0);
    }
    __syncthreads();   // all LDS reads done before epilogue reuses SMall

    const int bb = m0 >> 11, ssb = m0 & 2047;
    if (z == 2) {
        // V^T epilogue: LDS-transpose (xor-swizzled, 64n x 128m per half),
        // then coalesced 16B global stores along s.
#pragma unroll
        for (int half = 0; half < 2; half++) {
            if ((w >> 1) == half) {
#pragma unroll
                for (int j = 0; j < 4; j++) {
                    int n_l = j * 16 + c;                 // 0..63, n_l&15 == c
                    float bias_n = bias[n0 + half * 64 + n_l];
#pragma unroll
                    for (int i = 0; i < 4; i++) {
#pragma unroll
                        for (int r = 0; r < 4; r++) {
                            int m = wm + i * 16 + quad * 4 + r;
                            int ms = m ^ (c << 3);        // xor-swizzle chunks
                            SM[n_l * 128 + ms] = f2bf(acc[i][j][r] + bias_n);
                        }
                    }
                }
            }
            __syncthreads();
#pragma unroll
            for (int rb = 0; rb < 2; rb++) {
                int n_l = (t >> 3) + rb * 32;
                int ch = t & 7;
                int n_abs = n0 + half * 64 + n_l;
                int hh = n_abs >> 6, dd = n_abs & 63;
                unsigned short* dst =
                    Out + (((size_t)(bb * H_ + hh)) * 64 + dd) * S_ + ssb;
#pragma unroll
                for (int p = 0; p < 2; p++) {
                    int mc = ch + p * 8;
                    uint4 v = *(const uint4*)&SM[n_l * 128 + ((mc ^ (n_l & 15)) * 8)];
                    *(uint4*)&dst[mc * 8] = v;
                }
            }
            __syncthreads();
        }
    } else {
        // Q/K epilogue: [bh][s][d] rows contiguous in d (128B). Stage the
        // 128m x 64n half-tile ([m][8 chunks of 8], chunk ^= (m>>1)&7),
        // then 16B coalesced stores along d.
#pragma unroll
        for (int half = 0; half < 2; half++) {
            if ((w >> 1) == half) {
#pragma unroll
                for (int j = 0; j < 4; j++) {
                    float bias_n = bias[n0 + half * 64 + j * 16 + c];
#pragma unroll
                    for (int i = 0; i < 4; i++) {
#pragma unroll
                        for (int r = 0; r < 4; r++) {
                            int m = wm + i * 16 + quad * 4 + r;
                            int chunk = (j * 2 + (c >> 3)) ^ ((m >> 1) & 7);
                            SM[m * 64 + chunk * 8 + (c & 7)] =
                                f2bf((acc[i][j][r] + bias_n) * scale);
                        }
                    }
                }
            }
            __syncthreads();
            {
                int hh = (n0 >> 6) + half;
                unsigned short* dst =
                    Out + ((size_t)(bb * H_ + hh) * S_ + ssb) * 64;
#pragma unroll
                for (int i = 0; i < 4; i++) {
                    int idx = i * 256 + t;
                    int m = idx >> 3, ch = idx & 7;
                    uint4 v = *(const uint4*)&SM[m * 64 + ((ch ^ ((m >> 1) & 7)) * 8)];
                    *(uint4*)&dst[(size_t)m * 64 + ch * 8] = v;
                }
            }
            __syncthreads();
        }
    }
}

// ---------------- output projection GEMM ----------------
// 64x128 tile (grid 128x6 = 768 blocks = 3/CU), BK=32, double-buffered.
// Coalesced f32 epilogue via LDS transpose (4 n-quarters of 32 f32).
__global__ __launch_bounds__(256) void out_gemm(
    const unsigned short* __restrict__ Cb, const unsigned short* __restrict__ Wo,
    const float* __restrict__ bo, float* __restrict__ out)
{
    const int m0 = blockIdx.x * 64;
    const int n0 = blockIdx.y * 128;

    // dbuf: buf b -> As(2048) at b*6144, Bs(4096) at b*6144+2048
    __shared__ alignas(16) unsigned short SMall[12288];

    const int t = threadIdx.x;
    const int lane = t & 63, w = t >> 6;
    const int c = lane & 15, quad = lane >> 4;
    const int wm = (w & 1) * 32, wn = (w >> 1) * 64;

    const int arow = w * 16 + (lane >> 2);          // A stage row for this lane
    const int brow0 = (lane >> 2);                  // + chunk*16
    const int sc8 = (lane & 3) * 8;

    floatx4 acc[2][4];
#pragma unroll
    for (int i = 0; i < 2; i++)
#pragma unroll
        for (int j = 0; j < 4; j++) acc[i][j] = (floatx4){0.f, 0.f, 0.f, 0.f};

    // stage k-tile 0 into buf 0
    gload_lds16(&Cb[(size_t)(m0 + arow) * 768 + sc8], &SMall[w * 512]);
#pragma unroll
    for (int i = 0; i < 2; i++) {
        int chunk = i * 4 + w;
        gload_lds16(&Wo[(size_t)(n0 + chunk * 16 + brow0) * 768 + sc8],
                    &SMall[2048 + chunk * 512]);
    }

    for (int it = 0; it < 24; it++) {
        const int cur = it & 1;
        __syncthreads();
        if (it + 1 < 24) {
            int k1 = (it + 1) * 32;
            gload_lds16(&Cb[(size_t)(m0 + arow) * 768 + k1 + sc8],
                        &SMall[(cur ^ 1) * 6144 + w * 512]);
#pragma unroll
            for (int i = 0; i < 2; i++) {
                int chunk = i * 4 + w;
                gload_lds16(&Wo[(size_t)(n0 + chunk * 16 + brow0) * 768 + k1 + sc8],
                            &SMall[(cur ^ 1) * 6144 + 2048 + chunk * 512]);
            }
        }
        const unsigned short* As = &SMall[cur * 6144];
        const unsigned short* Bs = As + 2048;
        bf16x8 a[2], b[4];
#pragma unroll
        for (int i = 0; i < 2; i++)
            a[i] = *(const bf16x8*)&As[(wm + i * 16 + c) * 32 + quad * 8];
#pragma unroll
        for (int j = 0; j < 4; j++)
            b[j] = *(const bf16x8*)&Bs[(wn + j * 16 + c) * 32 + quad * 8];
#pragma unroll
        for (int i = 0; i < 2; i++)
#pragma unroll
            for (int j = 0; j < 4; j++)
                acc[i][j] = __builtin_amdgcn_mfma_f32_16x16x32_bf16(
                    a[i], b[j], acc[i][j], 0, 0, 0);
    }
    __syncthreads();

    float* SMf = (float*)SMall;    // 64m x 32n f32 = 8 KB per quarter
#pragma unroll
    for (int qtr = 0; qtr < 4; qtr++) {
        if ((w >> 1) == (qtr >> 1)) {
#pragma unroll
            for (int jj = 0; jj < 2; jj++) {
                int j = (qtr & 1) * 2 + jj;
                float bias_n = bo[n0 + wn + j * 16 + c];
                int chunk = jj * 4 + (c >> 2);
#pragma unroll
                for (int i = 0; i < 2; i++) {
#pragma unroll
                    for (int r = 0; r < 4; r++) {
                        int m = wm + i * 16 + quad * 4 + r;
                        SMf[m * 32 + ((chunk ^ (m & 7)) * 4) + (c & 3)] =
                            acc[i][j][r] + bias_n;
                    }
                }
            }
        }
        __syncthreads();
#pragma unroll
        for (int i = 0; i < 2; i++) {
            int idx = i * 256 + t;
            int m = idx >> 3, ch = idx & 7;
            float4 v = *(const float4*)&SMf[m * 32 + ((ch ^ (m & 7)) * 4)];
            *(float4*)&out[(size_t)(m0 + m) * 768 + n0 + qtr * 32 + ch * 4] = v;
        }
        __syncthreads();
    }
}

// ---------------- flash attention ----------------
// R7 = R6 (XCD swizzle, K-share nt-pairs, V-share, per-kt mask regs, no
// setprio) with SINGLE stride-64 XOR-swizzled Ps (8 KB, R2's verified
// layout): st=0's P written in the pair loop; st=1's 8 packed u32 held in
// registers, written after ap[0] is read, then ap[1] read from the same
// buffer. LDS 50176 -> 40960 = exactly 4 blocks/CU (160 KiB), +33% waves.
// Occupancy model: wave-slot class is (VGPR+AGPR) vs the 128 cliff (m69);
// here ~84+32 = 116 < 128 keeps the 4-wave class, so LDS is the binding
// limit and 40960 unlocks the 4th block.
__global__ __launch_bounds__(256) void attn(
    const unsigned short* __restrict__ Q, const unsigned short* __restrict__ K,
    const unsigned short* __restrict__ Vt,
    const unsigned long long* __restrict__ mbits,
    unsigned short* __restrict__ ctx)
{
    // XCD swizzle: dispatch order is x-fastest; lin % 8 = XCD.
    const int lin = blockIdx.y * 16 + blockIdx.x;      // 0..767
    const int nn = (lin & 7) * 96 + (lin >> 3);        // xcd * (768/8) + idx
    const int qt = nn & 15;                            // 0..15, 128 q-rows
    const int bh = nn >> 4;
    const int b = bh / H_, h = bh % H_;

    const unsigned short* Qp = Q + (size_t)bh * S_ * 64 + (size_t)qt * 128 * 64;
    const unsigned short* Kp = K + (size_t)bh * S_ * 64;
    const unsigned short* Vp = Vt + (size_t)bh * 64 * S_;   // [d][s]

    __shared__ alignas(16) unsigned short Ks[2][64 * 64];
    __shared__ alignas(16) unsigned short Vs[2][64 * 64];
    __shared__ alignas(16) unsigned short Ps[4][16 * 64];   // stride 64, swizzled

    const int t = threadIdx.x;
    const int lane = t & 63, w = t >> 6;
    const int c = lane & 15, quad = lane >> 4;

    bf16x8 aq[2][2];
#pragma unroll
    for (int st = 0; st < 2; st++) {
        aq[st][0] = *(const bf16x8*)&Qp[(size_t)(w * 32 + st * 16 + c) * 64 + quad * 8];
        aq[st][1] = *(const bf16x8*)&Qp[(size_t)(w * 32 + st * 16 + c) * 64 + 32 + quad * 8];
    }

    const unsigned long long* mrow =
        mbits + ((size_t)h * S_ + qt * 128 + w * 32 + quad * 4) * (S_ / 64);

    floatx4 acc_o[2][4];
#pragma unroll
    for (int st = 0; st < 2; st++)
#pragma unroll
        for (int i = 0; i < 4; i++) acc_o[st][i] = (floatx4){0.f, 0.f, 0.f, 0.f};
    float lp[2][4] = {{0.f, 0.f, 0.f, 0.f}, {0.f, 0.f, 0.f, 0.f}};

    const int srow = (lane >> 3);
    const int rc0 = ((quad     ) ^ (c & 7)) * 8;
    const int rc1 = ((quad + 4) ^ (c & 7)) * 8;

    // Ps swizzled addresses (write: per-r below; read: row c, chunk quad / quad+4)
    const int psr0 = c * 64 + ((quad ^ (c & 7)) << 3);
    const int psr1 = c * 64 + (((quad + 4) ^ (c & 7)) << 3);

#pragma unroll
    for (int i = 0; i < 2; i++) {
        int chunk = i * 4 + w;
        int row = chunk * 8 + srow;
        int col8 = (((lane & 7) ^ ((row >> 2) & 7))) * 8;
        gload_lds16(&Kp[(size_t)row * 64 + col8], &Ks[0][chunk * 512]);
        gload_lds16(&Vp[(size_t)row * S_ + col8], &Vs[0][chunk * 512]);
    }

    for (int kt = 0; kt < S_ / 64; kt++) {
        const int cur = kt & 1;
        __syncthreads();

        // mask words for THIS kt -> registers, issued BEFORE staging so
        // the softmax wait (FIFO oldest-first) doesn't drain staging.
        unsigned long long mk[2][4];
#pragma unroll
        for (int st = 0; st < 2; st++)
#pragma unroll
            for (int r = 0; r < 4; r++)
                mk[st][r] = mrow[st * 512 + r * 32 + kt];

        if (kt + 1 < S_ / 64) {
#pragma unroll
            for (int i = 0; i < 2; i++) {
                int chunk = i * 4 + w;
                int row = chunk * 8 + srow;
                int col8 = (((lane & 7) ^ ((row >> 2) & 7))) * 8;
                gload_lds16(&Kp[(size_t)((kt + 1) * 64 + row) * 64 + col8],
                            &Ks[cur ^ 1][chunk * 512]);
                gload_lds16(&Vp[(size_t)row * S_ + (kt + 1) * 64 + col8],
                            &Vs[cur ^ 1][chunk * 512]);
            }
        }

        // ---- K-shared QK^T in nt-pairs; st0 -> Ps, st1 -> registers ----
        unsigned int pk1[2][4];   // st=1 packed P, [p][r]
#pragma unroll
        for (int p = 0; p < 2; p++) {
            floatx4 zz[2][2];
            zz[0][0] = (floatx4){0.f, 0.f, 0.f, 0.f};
            zz[0][1] = (floatx4){0.f, 0.f, 0.f, 0.f};
            zz[1][0] = (floatx4){0.f, 0.f, 0.f, 0.f};
            zz[1][1] = (floatx4){0.f, 0.f, 0.f, 0.f};
#pragma unroll
            for (int q2 = 0; q2 < 2; q2++) {
                int kr = 4 * c + 2 * p + q2;
                bf16x8 bk0 = *(const bf16x8*)&Ks[cur][kr * 64 + rc0];
                bf16x8 bk1 = *(const bf16x8*)&Ks[cur][kr * 64 + rc1];
                zz[0][q2] = __builtin_amdgcn_mfma_f32_16x16x32_bf16(aq[0][0], bk0, zz[0][q2], 0, 0, 0);
                zz[0][q2] = __builtin_amdgcn_mfma_f32_16x16x32_bf16(aq[0][1], bk1, zz[0][q2], 0, 0, 0);
                zz[1][q2] = __builtin_amdgcn_mfma_f32_16x16x32_bf16(aq[1][0], bk0, zz[1][q2], 0, 0, 0);
                zz[1][q2] = __builtin_amdgcn_mfma_f32_16x16x32_bf16(aq[1][1], bk1, zz[1][q2], 0, 0, 0);
            }

            asm volatile("" ::: "memory");
#pragma unroll
            for (int r = 0; r < 4; r++) {
                unsigned int n2 = (unsigned int)(mk[0][r] >> (4 * c + 2 * p)) & 3u;
                float p0 = (n2 & 1u) ? __builtin_amdgcn_exp2f(zz[0][0][r]) : 0.f;
                float p1 = (n2 & 2u) ? __builtin_amdgcn_exp2f(zz[0][1][r]) : 0.f;
                lp[0][r] += p0 + p1;
                int row = quad * 4 + r;
                *(unsigned int*)&Ps[w][row * 64 + (((c >> 1) ^ (row & 7)) << 3) +
                                       ((c & 1) << 2) + 2 * p] = pk2bf(p0, p1);
            }
#pragma unroll
            for (int r = 0; r < 4; r++) {
                unsigned int n2 = (unsigned int)(mk[1][r] >> (4 * c + 2 * p)) & 3u;
                float p0 = (n2 & 1u) ? __builtin_amdgcn_exp2f(zz[1][0][r]) : 0.f;
                float p1 = (n2 & 2u) ? __builtin_amdgcn_exp2f(zz[1][1][r]) : 0.f;
                lp[1][r] += p0 + p1;
                pk1[p][r] = pk2bf(p0, p1);
            }
            asm volatile("" ::: "memory");
        }

        bf16x8 ap[2][2];
        ap[0][0] = *(const bf16x8*)&Ps[w][psr0];
        ap[0][1] = *(const bf16x8*)&Ps[w][psr1];
        asm volatile("" ::: "memory");   // ap0 reads before st1 overwrite
#pragma unroll
        for (int p = 0; p < 2; p++)
#pragma unroll
            for (int r = 0; r < 4; r++) {
                int row = quad * 4 + r;
                *(unsigned int*)&Ps[w][row * 64 + (((c >> 1) ^ (row & 7)) << 3) +
                                       ((c & 1) << 2) + 2 * p] = pk1[p][r];
            }
        asm volatile("" ::: "memory");
        ap[1][0] = *(const bf16x8*)&Ps[w][psr0];
        ap[1][1] = *(const bf16x8*)&Ps[w][psr1];

        // ---- shared-V PV: each bv fragment read once, feeds both st ----
#pragma unroll
        for (int nt = 0; nt < 4; nt++) {
            int vr = 4 * c + nt;                    // d = 4c+nt
            bf16x8 bv0 = *(const bf16x8*)&Vs[cur][vr * 64 + rc0];
            bf16x8 bv1 = *(const bf16x8*)&Vs[cur][vr * 64 + rc1];
#pragma unroll
            for (int st = 0; st < 2; st++) {
                acc_o[st][nt] = __builtin_amdgcn_mfma_f32_16x16x32_bf16(ap[st][0], bv0, acc_o[st][nt], 0, 0, 0);
                acc_o[st][nt] = __builtin_amdgcn_mfma_f32_16x16x32_bf16(ap[st][1], bv1, acc_o[st][nt], 0, 0, 0);
            }
        }
    }

#pragma unroll
    for (int st = 0; st < 2; st++)
#pragma unroll
        for (int r = 0; r < 4; r++) {
            float s = lp[st][r];
#pragma unroll
            for (int o = 1; o < 16; o <<= 1) s += __shfl_xor(s, o, 64);
            lp[st][r] = s;
        }

#pragma unroll
    for (int st = 0; st < 2; st++)
#pragma unroll
        for (int nt = 0; nt < 4; nt++)
#pragma unroll
            for (int r = 0; r < 4; r++) {
                int qrow = qt * 128 + w * 32 + st * 16 + quad * 4 + r;
                int dd = 4 * c + nt;
                float v = acc_o[st][nt][r] / lp[st][r];
                ctx[((size_t)b * S_ + qrow) * 768 + h * 64 + dd] = f2bf(v);
            }
}

extern "C" void kernel_launch(void* const* d_in, const int* in_sizes, int n_in,
                              void* d_out, int out_size, void* d_ws, size_t ws_size,
                              hipStream_t stream) {
    const float* hs    = (const float*)d_in[0];
    const int*   mask  = (const int*)d_in[1];
    const float* q_w   = (const float*)d_in[2];
    const float* q_b   = (const float*)d_in[3];
    const float* k_w   = (const float*)d_in[4];
    const float* k_b   = (const float*)d_in[5];
    const float* v_w   = (const float*)d_in[6];
    const float* v_b   = (const float*)d_in[7];
    const float* out_w = (const float*)d_in[8];
    const float* out_b = (const float*)d_in[9];
    float* out = (float*)d_out;

    // workspace layout (bf16 elements unless noted)
    unsigned short* Xb  = (unsigned short*)d_ws;       // 8192*768
    unsigned short* Wqb = Xb + 6291456;                // 768*768 each, x4 contiguous
    unsigned short* Wkb = Wqb + 589824;
    unsigned short* Wvb = Wkb + 589824;
    unsigned short* Wob = Wvb + 589824;
    unsigned short* Qb  = Wob + 589824;                // [B,H,S,HD]
    unsigned short* Kb  = Qb + 6291456;
    unsigned short* Vtb = Kb + 6291456;                // [B,H,HD,S] (transposed)
    unsigned short* Cb  = Vtb + 6291456;               // ctx [B,S,D]
    unsigned long long* mbits = (unsigned long long*)(Cb + 6291456); // H*S*(S/64)

    prep<<<57600, 256, 0, stream>>>(hs, q_w, k_w, v_w, out_w, mask, Xb, Wqb, mbits);
    qkv_gemm<<<dim3(64, 6, 3), 256, 0, stream>>>(Xb, Wqb, Wkb, Wvb,
                                                 q_b, k_b, v_b, Qb, Kb, Vtb);
    attn<<<dim3(16, 48), 256, 0, stream>>>(Qb, Kb, Vtb, mbits, Cb);
    out_gemm<<<dim3(128, 6), 256, 0, stream>>>(Cb, Wob, out_b, out);
}